// Round 7
// baseline (3833.372 us; speedup 1.0000x reference)
//
#include <hip/hip_runtime.h>

#define B_ROWS 8192
#define UNITS 512
#define NITER 25
#define INSZ 176
#define KPAD 128
#define GRAD_COLS 101

typedef __attribute__((ext_vector_type(8))) short short8;
typedef __attribute__((ext_vector_type(4))) float f32x4;
typedef __attribute__((ext_vector_type(8))) _Float16 half8;

__device__ __forceinline__ unsigned short f2h_bits(float f) {
  _Float16 h = (_Float16)f;
  return __builtin_bit_cast(unsigned short, h);
}
__device__ __forceinline__ float h2f_bits(unsigned short b) {
  return (float)__builtin_bit_cast(_Float16, b);
}
__device__ __forceinline__ float fast_tanh(float x) {
  float e = __expf(2.0f * x);
  return 1.0f - 2.0f / (e + 1.0f);
}

struct GArgs {
  const unsigned short *A;            // activations, fp16 plane, M x K
  const unsigned short *B;            // weights, fp16 plane, N x K (n-major)
  int K;
  const float* bias;
  const unsigned short *Hh;           // fwd activations for EPI1
  unsigned short *Oh;                 // output plane (fp16)
  float* Og;                          // grad output (EPI2)
  int iter;
};

// ---------------------------------------------------------------------------
// Weight prep: fp16 planes, n-major layouts, zero-padded.
// ---------------------------------------------------------------------------
__global__ __launch_bounds__(256)
void prep_kernel(const float* __restrict__ W0, const float* __restrict__ W1,
                 const float* __restrict__ W2, const float* __restrict__ W3,
                 unsigned short* TW0, unsigned short* TW1,
                 unsigned short* TW2, unsigned short* TW3,
                 unsigned short* CW0, unsigned short* CW1,
                 unsigned short* CW2, unsigned short* CW3)
{
  int id = blockIdx.x * 256 + threadIdx.x;
  if (id < 512 * KPAD) {
    int n = id >> 7, k = id & (KPAD - 1);
    TW0[id] = f2h_bits((k < 101) ? W0[(size_t)k * 512 + n] : 0.0f);
    int n2 = id >> 9, k2 = id & 511;
    CW0[id] = f2h_bits((n2 < 101) ? W0[(size_t)n2 * 512 + k2] : 0.0f);
  }
  {
    int n = id >> 9, k = id & 511;
    TW1[id] = f2h_bits(W1[(size_t)k * 512 + n]);
    TW2[id] = f2h_bits(W2[(size_t)k * 512 + n]);
    TW3[id] = f2h_bits(W3[(size_t)k * 512 + n]);
    CW1[id] = f2h_bits(W1[id]);
    CW2[id] = f2h_bits(W2[id]);
    CW3[id] = f2h_bits(W3[id]);
  }
}

// ---------------------------------------------------------------------------
// Initial build D_0 (8192 x 128, fp16), zero-padded cols 101..127
// ---------------------------------------------------------------------------
__global__ __launch_bounds__(256)
void build_d_kernel(const float* __restrict__ x, unsigned short* __restrict__ D)
{
  int id = blockIdx.x * 256 + threadIdx.x;     // [0, 8192*128)
  int b = id >> 7, c = id & 127;
  float val;
  if (c < 25)             val = x[(size_t)b * INSZ + c];
  else if (c < 100)       val = x[(size_t)b * INSZ + 26 + (c - 25)];
  else                    val = 0.0f;          // c==100 -> iter 0 == 0.0f
  D[id] = f2h_bits(val);
}

// ---------------------------------------------------------------------------
// Streaming GEMM: C[M x N] = A[M x K] @ B(n-major)[N x K], fp16.
// NO LDS. Both operands stream global->VGPR fragments; the MFMA fragment
// layout (16 rows x 64B per wave-instruction) is loaded directly with
// global_load_dwordx4 (fully 64B-granule coalesced). Intra-block operand
// duplication (2x2 wave grid) is served by L1; inter-block A-panel sharing
// by co-XCD L2 (id swizzle: 4 bn-blocks of one A-panel share id%8).
// 4-deep named fragment ring (F0..F3, static indexing) gives each load a
// 4-K-step (~600 cyc) lead; compiler scoreboards all waits precisely.
// A bare s_barrier every 4 K-steps bounds wave drift (L1 reuse), and with
// no shared state the kernel is replay-safe by construction.
// ---------------------------------------------------------------------------
struct Frag { short8 a[4], b[4]; };

__device__ __forceinline__ Frag loadf(const unsigned short* Ab, const unsigned short* Bb,
                                      int K, int ks) {
  Frag f;
#pragma unroll
  for (int i = 0; i < 4; ++i) {
    f.a[i] = *(const short8*)(Ab + (size_t)i * 16 * K + ks * 32);
    f.b[i] = *(const short8*)(Bb + (size_t)i * 16 * K + ks * 32);
  }
  return f;
}

__device__ __forceinline__ void mfma_step(const Frag& f, f32x4 (&acc)[4][4]) {
#pragma unroll
  for (int mi = 0; mi < 4; ++mi)
#pragma unroll
    for (int ni = 0; ni < 4; ++ni)
      acc[mi][ni] = __builtin_amdgcn_mfma_f32_16x16x32_f16(
          __builtin_bit_cast(half8, f.a[mi]), __builtin_bit_cast(half8, f.b[ni]),
          acc[mi][ni], 0, 0, 0);
}

template<int EPI>
__device__ __forceinline__ void gemm_body(const GArgs g, int id)
{
  const int t = threadIdx.x;
  const int w = t >> 6;
  const int lane = t & 63;
  const int l15 = lane & 15, l4 = lane >> 4;
  const int bm = (EPI == 2) ? id : ((id & 7) | ((id >> 5) << 3));
  const int bn = (EPI == 2) ? 0  : ((id >> 3) & 3);
  const int wm = (w >> 1) * 64, wn = (w & 1) * 64;
  const int K = g.K;
  const int NK = K >> 5;               // 32-wide K-steps
  f32x4 acc[4][4] = {};

  // per-lane fragment base addresses (fragment: row = base_row + mi*16 + l15,
  // 8 halves at k = ks*32 + l4*8)
  const unsigned short* Ab = g.A + ((size_t)(bm * 128 + wm + l15) * K + l4 * 8);
  const unsigned short* Bb = g.B + ((size_t)(bn * 128 + wn + l15) * K + l4 * 8);

  Frag F0 = loadf(Ab, Bb, K, 0);
  Frag F1 = loadf(Ab, Bb, K, 1);
  Frag F2 = loadf(Ab, Bb, K, 2);
  Frag F3 = loadf(Ab, Bb, K, 3);

  const int NJ = NK >> 2;              // macro-iters of 4 K-steps
  for (int j = 0; j < NJ; ++j) {
    int nb = j * 4 + 4;
    mfma_step(F0, acc); if (nb + 0 < NK) F0 = loadf(Ab, Bb, K, nb + 0);
    mfma_step(F1, acc); if (nb + 1 < NK) F1 = loadf(Ab, Bb, K, nb + 1);
    mfma_step(F2, acc); if (nb + 2 < NK) F2 = loadf(Ab, Bb, K, nb + 2);
    mfma_step(F3, acc); if (nb + 3 < NK) F3 = loadf(Ab, Bb, K, nb + 3);
    __builtin_amdgcn_s_barrier();      // rendezvous only: bound wave drift
  }

  const int gm0 = bm * 128 + wm;
  const int gn0 = bn * 128 + wn;
#pragma unroll
  for (int mi = 0; mi < 4; ++mi) {
#pragma unroll
    for (int ni = 0; ni < 4; ++ni) {
      int n = gn0 + ni * 16 + l15;
#pragma unroll
      for (int r = 0; r < 4; ++r) {
        int m = gm0 + mi * 16 + l4 * 4 + r;
        float v = acc[mi][ni][r];
        if constexpr (EPI == 0) {
          float h = fast_tanh(v + g.bias[n]);
          g.Oh[(size_t)m * UNITS + n] = f2h_bits(h);
        } else if constexpr (EPI == 1) {
          size_t idx = (size_t)m * UNITS + n;
          float h = h2f_bits(g.Hh[idx]);
          g.Oh[idx] = f2h_bits(v * (1.0f - h * h));
        } else {
          if (n < GRAD_COLS)
            g.Og[((size_t)m * NITER + g.iter) * GRAD_COLS + n] = v;
        }
      }
    }
  }
}

template<int EA, int EB>
__global__ __launch_bounds__(256, 2)
void paired_kernel(GArgs A, GArgs B, int nA) {
  int id = blockIdx.x;
  if (id < nA) gemm_body<EA>(A, id);
  else         gemm_body<EB>(B, id - nA);
}

template<int E>
__global__ __launch_bounds__(256, 2)
void solo_kernel(GArgs A) {
  gemm_body<E>(A, blockIdx.x);
}

// ---------------------------------------------------------------------------
// dot (w[:,i] = H3.W4 + b4) + U3 = (1-H3^2)*W4 + build D for iter i+1
// ---------------------------------------------------------------------------
__global__ __launch_bounds__(256)
void dot_bd_kernel(const unsigned short* __restrict__ H3,
                   const float* __restrict__ W4, const float* __restrict__ b4,
                   const float* __restrict__ x, float* __restrict__ w_out,
                   unsigned short* __restrict__ U,
                   unsigned short* __restrict__ D,
                   int iter, int buildD)
{
  int w = threadIdx.x >> 6, lane = threadIdx.x & 63;
  int b = blockIdx.x * 4 + w;
  size_t base = (size_t)b * UNITS + lane * 8;
  short8 vh = *(const short8*)&H3[base];
  float dot = 0.0f;
  short8 ou;
#pragma unroll
  for (int j = 0; j < 8; ++j) {
    float h = h2f_bits((unsigned short)vh[j]);
    float g = W4[lane * 8 + j];
    dot += h * g;
    ou[j] = (short)f2h_bits((1.0f - h * h) * g);
  }
  *(short8*)&U[base] = ou;
#pragma unroll
  for (int off = 1; off < 64; off <<= 1) dot += __shfl_xor(dot, off);
  float wv = dot + b4[0];
  if (lane == 0) w_out[(size_t)b * NITER + iter] = wv;

  if (buildD) {
    int jn = iter + 1;
#pragma unroll
    for (int cc = 0; cc < 2; ++cc) {
      int c = lane + cc * 64;
      float val;
      if (c < 25 - jn)        val = x[(size_t)b * INSZ + jn + c];
      else if (c < 24)        val = w_out[(size_t)b * NITER + (c - (25 - jn))];
      else if (c == 24)       val = wv;      // w[:, jn-1] just computed, in-register
      else if (c < 100)       val = x[(size_t)b * INSZ + 26 + 3 * jn + (c - 25)];
      else if (c == 100)      val = (float)jn;
      else                    val = 0.0f;
      D[(size_t)b * KPAD + c] = f2h_bits(val);
    }
  }
}

// ---------------------------------------------------------------------------
extern "C" void kernel_launch(void* const* d_in, const int* in_sizes, int n_in,
                              void* d_out, int out_size, void* d_ws, size_t ws_size,
                              hipStream_t stream) {
  const float* x  = (const float*)d_in[0];
  const float* W0 = (const float*)d_in[1];
  const float* b0 = (const float*)d_in[2];
  const float* W1 = (const float*)d_in[3];
  const float* b1 = (const float*)d_in[4];
  const float* W2 = (const float*)d_in[5];
  const float* b2 = (const float*)d_in[6];
  const float* W3 = (const float*)d_in[7];
  const float* b3 = (const float*)d_in[8];
  const float* W4 = (const float*)d_in[9];
  const float* b4 = (const float*)d_in[10];

  float* w_out    = (float*)d_out;                              // (8192, 25)
  float* grad_out = (float*)d_out + (size_t)B_ROWS * NITER;     // (8192, 25, 101)

  char* p = (char*)d_ws;
  auto alloc = [&](size_t elems) { unsigned short* r = (unsigned short*)p; p += elems * 2; return r; };

  unsigned short* TW0 = alloc(512 * KPAD);
  unsigned short* TW1 = alloc(512 * 512);
  unsigned short* TW2 = alloc(512 * 512);
  unsigned short* TW3 = alloc(512 * 512);
  unsigned short* CW0 = alloc(KPAD * 512);
  unsigned short* CW1 = alloc(512 * 512);
  unsigned short* CW2 = alloc(512 * 512);
  unsigned short* CW3 = alloc(512 * 512);

  unsigned short* D = alloc((size_t)B_ROWS * KPAD);

  unsigned short *H[2][4];
  for (int par = 0; par < 2; ++par)
    for (int l = 0; l < 4; ++l)
      H[par][l] = alloc((size_t)B_ROWS * UNITS);
  unsigned short* Ua = alloc((size_t)B_ROWS * UNITS);
  unsigned short* Ub = alloc((size_t)B_ROWS * UNITS);

  prep_kernel<<<1024, 256, 0, stream>>>(W0, W1, W2, W3,
      TW0, TW1, TW2, TW3, CW0, CW1, CW2, CW3);

  build_d_kernel<<<4096, 256, 0, stream>>>(x, D);

  // forward chain for iteration 0 (parity 0)
  {
    GArgs f0 = {D, TW0, KPAD, b0, nullptr, H[0][0], nullptr, 0};
    GArgs f1 = {H[0][0], TW1, 512, b1, nullptr, H[0][1], nullptr, 0};
    GArgs f2 = {H[0][1], TW2, 512, b2, nullptr, H[0][2], nullptr, 0};
    GArgs f3 = {H[0][2], TW3, 512, b3, nullptr, H[0][3], nullptr, 0};
    solo_kernel<0><<<256, 256, 0, stream>>>(f0);
    solo_kernel<0><<<256, 256, 0, stream>>>(f1);
    solo_kernel<0><<<256, 256, 0, stream>>>(f2);
    solo_kernel<0><<<256, 256, 0, stream>>>(f3);
  }

  for (int i = 0; i < NITER; ++i) {
    int pp = i & 1, q = pp ^ 1;
    bool more = (i < NITER - 1);

    dot_bd_kernel<<<2048, 256, 0, stream>>>(H[pp][3], W4, b4, x, w_out,
                                            Ua, D, i, more ? 1 : 0);

    GArgs bw3 = {Ua, CW3, 512, nullptr, H[pp][2], Ub, nullptr, 0};
    GArgs bw2 = {Ub, CW2, 512, nullptr, H[pp][1], Ua, nullptr, 0};
    GArgs bw1 = {Ua, CW1, 512, nullptr, H[pp][0], Ub, nullptr, 0};
    GArgs gr0 = {Ub, CW0, 512, nullptr, nullptr, nullptr, grad_out, i};

    if (more) {
      GArgs f0 = {D, TW0, KPAD, b0, nullptr, H[q][0], nullptr, 0};
      GArgs f1 = {H[q][0], TW1, 512, b1, nullptr, H[q][1], nullptr, 0};
      GArgs f2 = {H[q][1], TW2, 512, b2, nullptr, H[q][2], nullptr, 0};
      GArgs f3 = {H[q][2], TW3, 512, b3, nullptr, H[q][3], nullptr, 0};
      paired_kernel<1, 0><<<512, 256, 0, stream>>>(bw3, f0, 256);
      paired_kernel<1, 0><<<512, 256, 0, stream>>>(bw2, f1, 256);
      paired_kernel<1, 0><<<512, 256, 0, stream>>>(bw1, f2, 256);
      paired_kernel<2, 0><<<320, 256, 0, stream>>>(gr0, f3, 64);
    } else {
      solo_kernel<1><<<256, 256, 0, stream>>>(bw3);
      solo_kernel<1><<<256, 256, 0, stream>>>(bw2);
      solo_kernel<1><<<256, 256, 0, stream>>>(bw1);
      solo_kernel<2><<<64, 256, 0, stream>>>(gr0);
    }
  }

  (void)in_sizes; (void)n_in; (void)out_size; (void)ws_size;
}

// Round 8
// 2228.325 us; speedup vs baseline: 1.7203x; 1.7203x over previous
//
#include <hip/hip_runtime.h>

#define B_ROWS 8192
#define UNITS 512
#define NITER 25
#define INSZ 176
#define KPAD 128
#define GRAD_COLS 101

typedef __attribute__((ext_vector_type(8))) short short8;
typedef __attribute__((ext_vector_type(4))) float f32x4;
typedef __attribute__((ext_vector_type(8))) _Float16 half8;

__device__ __forceinline__ unsigned short f2h_bits(float f) {
  _Float16 h = (_Float16)f;
  return __builtin_bit_cast(unsigned short, h);
}
__device__ __forceinline__ float h2f_bits(unsigned short b) {
  return (float)__builtin_bit_cast(_Float16, b);
}
__device__ __forceinline__ float fast_tanh(float x) {
  float e = __expf(2.0f * x);
  return 1.0f - 2.0f / (e + 1.0f);
}

typedef __attribute__((address_space(3))) unsigned int lds_u32;
typedef __attribute__((address_space(1))) const unsigned int glb_u32;
__device__ __forceinline__ void gload16(const void* g, void* l) {
  __builtin_amdgcn_global_load_lds((glb_u32*)g, (lds_u32*)l, 16, 0, 0);
}

struct GArgs {
  const unsigned short *A;            // activations, fp16 plane, M x K
  const unsigned short *B;            // weights, fp16 plane, N x K (n-major)
  int K;
  const float* bias;
  const unsigned short *Hh;           // fwd activations for EPI1
  unsigned short *Oh;                 // output plane (fp16)
  float* Og;                          // grad output (EPI2)
  int iter;
};

// ---------------------------------------------------------------------------
// Weight prep: fp16 planes, n-major layouts, zero-padded.
// ---------------------------------------------------------------------------
__global__ __launch_bounds__(256)
void prep_kernel(const float* __restrict__ W0, const float* __restrict__ W1,
                 const float* __restrict__ W2, const float* __restrict__ W3,
                 unsigned short* TW0, unsigned short* TW1,
                 unsigned short* TW2, unsigned short* TW3,
                 unsigned short* CW0, unsigned short* CW1,
                 unsigned short* CW2, unsigned short* CW3)
{
  int id = blockIdx.x * 256 + threadIdx.x;
  if (id < 512 * KPAD) {
    int n = id >> 7, k = id & (KPAD - 1);
    TW0[id] = f2h_bits((k < 101) ? W0[(size_t)k * 512 + n] : 0.0f);
    int n2 = id >> 9, k2 = id & 511;
    CW0[id] = f2h_bits((n2 < 101) ? W0[(size_t)n2 * 512 + k2] : 0.0f);
  }
  {
    int n = id >> 9, k = id & 511;
    TW1[id] = f2h_bits(W1[(size_t)k * 512 + n]);
    TW2[id] = f2h_bits(W2[(size_t)k * 512 + n]);
    TW3[id] = f2h_bits(W3[(size_t)k * 512 + n]);
    CW1[id] = f2h_bits(W1[id]);
    CW2[id] = f2h_bits(W2[id]);
    CW3[id] = f2h_bits(W3[id]);
  }
}

// ---------------------------------------------------------------------------
// Initial build D_0 (8192 x 128, fp16), zero-padded cols 101..127
// ---------------------------------------------------------------------------
__global__ __launch_bounds__(256)
void build_d_kernel(const float* __restrict__ x, unsigned short* __restrict__ D)
{
  int id = blockIdx.x * 256 + threadIdx.x;     // [0, 8192*128)
  int b = id >> 7, c = id & 127;
  float val;
  if (c < 25)             val = x[(size_t)b * INSZ + c];
  else if (c < 100)       val = x[(size_t)b * INSZ + 26 + (c - 25)];
  else                    val = 0.0f;          // c==100 -> iter 0 == 0.0f
  D[id] = f2h_bits(val);
}

// ---------------------------------------------------------------------------
// GEMM body: C[M x N] = A[M x K] @ B(n-major)[N x K], fp16 single product.
// 256x128 tile, BK=64, 8 waves (4m x 2n, 64x64 each), 512 threads,
// double-buffered LDS (2 x 48KB), counted-vmcnt 2-barrier pipeline
// (round-6 sync structure; m230 evidence: 8-wave 1-block/CU 2-phase beats
// 2x 4-wave blocks at same waves/SIMD by amortizing barrier events).
//   per K-step: { stage(ks+1)->other buf ; vmcnt(6) [only stage(ks)] ;
//                 barrier ; compute(ks) ; lgkmcnt(0)+sched_barrier ; barrier }
// EPI 0: tanh(acc+bias) (128 blocks/GEMM)  EPI 1: acc*(1-h^2) (128)
// EPI 2: grad store n<101 (32 blocks)
// ---------------------------------------------------------------------------
template<int EPI>
__device__ __forceinline__ void gemm_body(const GArgs g, short* smem, int id)
{
  const int t = threadIdx.x;
  const int w = t >> 6;                 // 0..7
  const int lane = t & 63;
  const int l15 = lane & 15, l4 = lane >> 4;
  // 128 blocks/GEMM: bm = 5 bits from (b2b1b0 | b6b5), bn = (b4b3).
  // 4 bn-blocks sharing an A-panel (same bm) have the same id%8 -> same XCD.
  const int bm = (EPI == 2) ? id : ((id & 7) | ((id >> 5) << 3));
  const int bn = (EPI == 2) ? 0  : ((id >> 3) & 3);
  const int wm = (w >> 1) * 64;         // 0..192 within 256-row A region
  const int wn = (w & 1) * 64;          // 0/64 within 128-row B region
  const int K = g.K;
  const int NK = K >> 6;
  f32x4 acc[4][4] = {};

  const int sr = t >> 3;   // 0..63 (row within 64-row round)
  const int ss = t & 7;    // linear 16B slot within 128B row

  // stage K-step ks into buffer buf: A 256x64 (16384 sh) + B 128x64 (8192 sh)
  // 6 gload16 per thread (4 A rounds + 2 B rounds)
  auto stage = [&](int ks, int buf) {
    short* As = smem + buf * 24576;
    short* Bs = As + 16384;
    int kc = ks << 6;
#pragma unroll
    for (int q = 0; q < 4; ++q) {
      int r = q * 64 + sr;
      int c = ss ^ (r & 7);                          // inverse-swizzled source slot
      size_t ga = (size_t)(bm * 256 + r) * K + kc + c * 8;
      gload16(g.A + ga, &As[q * 4096 + w * 512]);    // wave-uniform LDS base
    }
#pragma unroll
    for (int q = 0; q < 2; ++q) {
      int r = q * 64 + sr;
      int c = ss ^ (r & 7);
      size_t gb = (size_t)(bn * 128 + r) * K + kc + c * 8;
      gload16(g.B + gb, &Bs[q * 4096 + w * 512]);
    }
  };

  stage(0, 0);

  for (int ks = 0; ks < NK; ++ks) {
    if (ks + 1 < NK) {
      stage(ks + 1, (ks + 1) & 1);
      // wait only for stage(ks): exactly the 6 loads of stage(ks+1) remain
      asm volatile("s_waitcnt vmcnt(6)" ::: "memory");
    } else {
      asm volatile("s_waitcnt vmcnt(0)" ::: "memory");
    }
    __builtin_amdgcn_sched_barrier(0);
    __builtin_amdgcn_s_barrier();        // all waves' stage(ks) visible

    const short* As = smem + (ks & 1) * 24576;
    const short* Bs = As + 16384;
#pragma unroll
    for (int kk = 0; kk < 2; ++kk) {
      short8 av[4], bh[4];
#pragma unroll
      for (int mi = 0; mi < 4; ++mi) {
        int row = wm + mi * 16 + l15;
        int eoff = row * 64 + (((kk * 4 + l4) ^ (row & 7)) << 3);
        av[mi] = *(const short8*)&As[eoff];
      }
#pragma unroll
      for (int ni = 0; ni < 4; ++ni) {
        int row = wn + ni * 16 + l15;
        int eoff = row * 64 + (((kk * 4 + l4) ^ (row & 7)) << 3);
        bh[ni] = *(const short8*)&Bs[eoff];
      }
#pragma unroll
      for (int mi = 0; mi < 4; ++mi)
#pragma unroll
        for (int ni = 0; ni < 4; ++ni)
          acc[mi][ni] = __builtin_amdgcn_mfma_f32_16x16x32_f16(
              __builtin_bit_cast(half8, av[mi]), __builtin_bit_cast(half8, bh[ni]),
              acc[mi][ni], 0, 0, 0);
    }
    // my reads of buf[ks&1] retired (rule #18: asm wait + sched fence), then
    // barrier -> all waves done reading; next iteration may overwrite it.
    asm volatile("s_waitcnt lgkmcnt(0)" ::: "memory");
    __builtin_amdgcn_sched_barrier(0);
    __builtin_amdgcn_s_barrier();
  }

  const int gm0 = bm * 256 + wm;
  const int gn0 = bn * 128 + wn;
#pragma unroll
  for (int mi = 0; mi < 4; ++mi) {
#pragma unroll
    for (int ni = 0; ni < 4; ++ni) {
      int n = gn0 + ni * 16 + l15;
#pragma unroll
      for (int r = 0; r < 4; ++r) {
        int m = gm0 + mi * 16 + l4 * 4 + r;
        float v = acc[mi][ni][r];
        if constexpr (EPI == 0) {
          float h = fast_tanh(v + g.bias[n]);
          g.Oh[(size_t)m * UNITS + n] = f2h_bits(h);
        } else if constexpr (EPI == 1) {
          size_t idx = (size_t)m * UNITS + n;
          float h = h2f_bits(g.Hh[idx]);
          g.Oh[idx] = f2h_bits(v * (1.0f - h * h));
        } else {
          if (n < GRAD_COLS)
            g.Og[((size_t)m * NITER + g.iter) * GRAD_COLS + n] = v;
        }
      }
    }
  }
}

template<int EA, int EB>
__global__ __launch_bounds__(512, 2)
void paired_kernel(GArgs A, GArgs B, int nA) {
  __shared__ short smem[49152];        // 2 bufs x (A 16384 + B 8192) = 96KB
  int id = blockIdx.x;
  if (id < nA) gemm_body<EA>(A, smem, id);
  else         gemm_body<EB>(B, smem, id - nA);
}

template<int E>
__global__ __launch_bounds__(512, 2)
void solo_kernel(GArgs A) {
  __shared__ short smem[49152];
  gemm_body<E>(A, smem, blockIdx.x);
}

// ---------------------------------------------------------------------------
// dot (w[:,i] = H3.W4 + b4) + U3 = (1-H3^2)*W4 + build D for iter i+1
// ---------------------------------------------------------------------------
__global__ __launch_bounds__(256)
void dot_bd_kernel(const unsigned short* __restrict__ H3,
                   const float* __restrict__ W4, const float* __restrict__ b4,
                   const float* __restrict__ x, float* __restrict__ w_out,
                   unsigned short* __restrict__ U,
                   unsigned short* __restrict__ D,
                   int iter, int buildD)
{
  int w = threadIdx.x >> 6, lane = threadIdx.x & 63;
  int b = blockIdx.x * 4 + w;
  size_t base = (size_t)b * UNITS + lane * 8;
  short8 vh = *(const short8*)&H3[base];
  float dot = 0.0f;
  short8 ou;
#pragma unroll
  for (int j = 0; j < 8; ++j) {
    float h = h2f_bits((unsigned short)vh[j]);
    float g = W4[lane * 8 + j];
    dot += h * g;
    ou[j] = (short)f2h_bits((1.0f - h * h) * g);
  }
  *(short8*)&U[base] = ou;
#pragma unroll
  for (int off = 1; off < 64; off <<= 1) dot += __shfl_xor(dot, off);
  float wv = dot + b4[0];
  if (lane == 0) w_out[(size_t)b * NITER + iter] = wv;

  if (buildD) {
    int jn = iter + 1;
#pragma unroll
    for (int cc = 0; cc < 2; ++cc) {
      int c = lane + cc * 64;
      float val;
      if (c < 25 - jn)        val = x[(size_t)b * INSZ + jn + c];
      else if (c < 24)        val = w_out[(size_t)b * NITER + (c - (25 - jn))];
      else if (c == 24)       val = wv;      // w[:, jn-1] just computed, in-register
      else if (c < 100)       val = x[(size_t)b * INSZ + 26 + 3 * jn + (c - 25)];
      else if (c == 100)      val = (float)jn;
      else                    val = 0.0f;
      D[(size_t)b * KPAD + c] = f2h_bits(val);
    }
  }
}

// ---------------------------------------------------------------------------
extern "C" void kernel_launch(void* const* d_in, const int* in_sizes, int n_in,
                              void* d_out, int out_size, void* d_ws, size_t ws_size,
                              hipStream_t stream) {
  const float* x  = (const float*)d_in[0];
  const float* W0 = (const float*)d_in[1];
  const float* b0 = (const float*)d_in[2];
  const float* W1 = (const float*)d_in[3];
  const float* b1 = (const float*)d_in[4];
  const float* W2 = (const float*)d_in[5];
  const float* b2 = (const float*)d_in[6];
  const float* W3 = (const float*)d_in[7];
  const float* b3 = (const float*)d_in[8];
  const float* W4 = (const float*)d_in[9];
  const float* b4 = (const float*)d_in[10];

  float* w_out    = (float*)d_out;                              // (8192, 25)
  float* grad_out = (float*)d_out + (size_t)B_ROWS * NITER;     // (8192, 25, 101)

  char* p = (char*)d_ws;
  auto alloc = [&](size_t elems) { unsigned short* r = (unsigned short*)p; p += elems * 2; return r; };

  unsigned short* TW0 = alloc(512 * KPAD);
  unsigned short* TW1 = alloc(512 * 512);
  unsigned short* TW2 = alloc(512 * 512);
  unsigned short* TW3 = alloc(512 * 512);
  unsigned short* CW0 = alloc(KPAD * 512);
  unsigned short* CW1 = alloc(512 * 512);
  unsigned short* CW2 = alloc(512 * 512);
  unsigned short* CW3 = alloc(512 * 512);

  unsigned short* D = alloc((size_t)B_ROWS * KPAD);

  unsigned short *H[2][4];
  for (int par = 0; par < 2; ++par)
    for (int l = 0; l < 4; ++l)
      H[par][l] = alloc((size_t)B_ROWS * UNITS);
  unsigned short* Ua = alloc((size_t)B_ROWS * UNITS);
  unsigned short* Ub = alloc((size_t)B_ROWS * UNITS);

  prep_kernel<<<1024, 256, 0, stream>>>(W0, W1, W2, W3,
      TW0, TW1, TW2, TW3, CW0, CW1, CW2, CW3);

  build_d_kernel<<<4096, 256, 0, stream>>>(x, D);

  // forward chain for iteration 0 (parity 0)
  {
    GArgs f0 = {D, TW0, KPAD, b0, nullptr, H[0][0], nullptr, 0};
    GArgs f1 = {H[0][0], TW1, 512, b1, nullptr, H[0][1], nullptr, 0};
    GArgs f2 = {H[0][1], TW2, 512, b2, nullptr, H[0][2], nullptr, 0};
    GArgs f3 = {H[0][2], TW3, 512, b3, nullptr, H[0][3], nullptr, 0};
    solo_kernel<0><<<128, 512, 0, stream>>>(f0);
    solo_kernel<0><<<128, 512, 0, stream>>>(f1);
    solo_kernel<0><<<128, 512, 0, stream>>>(f2);
    solo_kernel<0><<<128, 512, 0, stream>>>(f3);
  }

  for (int i = 0; i < NITER; ++i) {
    int pp = i & 1, q = pp ^ 1;
    bool more = (i < NITER - 1);

    dot_bd_kernel<<<2048, 256, 0, stream>>>(H[pp][3], W4, b4, x, w_out,
                                            Ua, D, i, more ? 1 : 0);

    GArgs bw3 = {Ua, CW3, 512, nullptr, H[pp][2], Ub, nullptr, 0};
    GArgs bw2 = {Ub, CW2, 512, nullptr, H[pp][1], Ua, nullptr, 0};
    GArgs bw1 = {Ua, CW1, 512, nullptr, H[pp][0], Ub, nullptr, 0};
    GArgs gr0 = {Ub, CW0, 512, nullptr, nullptr, nullptr, grad_out, i};

    if (more) {
      GArgs f0 = {D, TW0, KPAD, b0, nullptr, H[q][0], nullptr, 0};
      GArgs f1 = {H[q][0], TW1, 512, b1, nullptr, H[q][1], nullptr, 0};
      GArgs f2 = {H[q][1], TW2, 512, b2, nullptr, H[q][2], nullptr, 0};
      GArgs f3 = {H[q][2], TW3, 512, b3, nullptr, H[q][3], nullptr, 0};
      paired_kernel<1, 0><<<256, 512, 0, stream>>>(bw3, f0, 128);
      paired_kernel<1, 0><<<256, 512, 0, stream>>>(bw2, f1, 128);
      paired_kernel<1, 0><<<256, 512, 0, stream>>>(bw1, f2, 128);
      paired_kernel<2, 0><<<160, 512, 0, stream>>>(gr0, f3, 32);
    } else {
      solo_kernel<1><<<128, 512, 0, stream>>>(bw3);
      solo_kernel<1><<<128, 512, 0, stream>>>(bw2);
      solo_kernel<1><<<128, 512, 0, stream>>>(bw1);
      solo_kernel<2><<<32, 512, 0, stream>>>(gr0);
    }
  }

  (void)in_sizes; (void)n_in; (void)out_size; (void)ws_size;
}